// Round 7
// baseline (560.009 us; speedup 1.0000x reference)
//
#include <hip/hip_runtime.h>
#include <hip/hip_bf16.h>
#include <math.h>

// Problem constants
#define S 2048
#define HID 2048
#define NH 16
#define KVH 8
#define HD 128
#define EPS 1e-6f
#define QK_SCALE 11.313708498984760390f  // 1/SCALING = sqrt(128)

typedef __attribute__((ext_vector_type(8))) short s16x8;
typedef __attribute__((ext_vector_type(4))) float f32x4;

__device__ __forceinline__ unsigned short f2bf(float f) {
  __hip_bfloat16 h = __float2bfloat16(f);
  return *(unsigned short*)&h;
}
__device__ __forceinline__ float bf2f(unsigned short u) {
  unsigned int x = ((unsigned int)u) << 16;
  return __builtin_bit_cast(float, x);
}

__device__ __forceinline__ void gload16(const void* g, void* l) {
  __builtin_amdgcn_global_load_lds(
      (const __attribute__((address_space(1))) void*)g,
      (__attribute__((address_space(3))) void*)l, 16, 0, 0);
}

// ---------------------------------------------------------------------------
// fp32 -> split bf16 (hi + lo) elementwise.
// ---------------------------------------------------------------------------
__global__ __launch_bounds__(256) void f32_to_bf16_split(const float* __restrict__ in,
                                                         unsigned short* __restrict__ hi,
                                                         unsigned short* __restrict__ lo,
                                                         int n4) {
  const int i = blockIdx.x * 256 + threadIdx.x;
  if (i < n4) {
    const float4 v = *(const float4*)(in + (size_t)i * 4);
    ushort4 h, l;
    h.x = f2bf(v.x); l.x = f2bf(v.x - bf2f(h.x));
    h.y = f2bf(v.y); l.y = f2bf(v.y - bf2f(h.y));
    h.z = f2bf(v.z); l.z = f2bf(v.z - bf2f(h.z));
    h.w = f2bf(v.w); l.w = f2bf(v.w - bf2f(h.w));
    *(ushort4*)(hi + (size_t)i * 4) = h;
    *(ushort4*)(lo + (size_t)i * 4) = l;
  }
}

// ---------------------------------------------------------------------------
// Transpose fp32 [K][N] -> bf16 [N][K], plain.
// ---------------------------------------------------------------------------
__global__ __launch_bounds__(256) void transpose_to_bf16(const float* __restrict__ in,
                                                         unsigned short* __restrict__ out,
                                                         int K, int N) {
  __shared__ float t[64][65];
  const int n0 = blockIdx.x * 64;
  const int k0 = blockIdx.y * 64;
  const int tid = threadIdx.x;

  for (int idx = tid; idx < 64 * 16; idx += 256) {
    const int r = idx >> 4;
    const int c4 = (idx & 15) * 4;
    const float4 v = *(const float4*)(in + (size_t)(k0 + r) * N + n0 + c4);
    t[r][c4 + 0] = v.x; t[r][c4 + 1] = v.y; t[r][c4 + 2] = v.z; t[r][c4 + 3] = v.w;
  }
  __syncthreads();
  for (int idx = tid; idx < 64 * 16; idx += 256) {
    const int a = idx >> 4;
    const int b4 = (idx & 15) * 4;
    ushort4 u;
    u.x = f2bf(t[b4 + 0][a]); u.y = f2bf(t[b4 + 1][a]);
    u.z = f2bf(t[b4 + 2][a]); u.w = f2bf(t[b4 + 3][a]);
    *(ushort4*)(out + (size_t)(n0 + a) * K + k0 + b4) = u;
  }
}

// ---------------------------------------------------------------------------
// Transpose fp32 [K][N] -> split bf16 hi/lo [N][K].
// ---------------------------------------------------------------------------
__global__ __launch_bounds__(256) void transpose_to_bf16_split(const float* __restrict__ in,
                                                               unsigned short* __restrict__ ohi,
                                                               unsigned short* __restrict__ olo,
                                                               int K, int N) {
  __shared__ float t[64][65];
  const int n0 = blockIdx.x * 64;
  const int k0 = blockIdx.y * 64;
  const int tid = threadIdx.x;

  for (int idx = tid; idx < 64 * 16; idx += 256) {
    const int r = idx >> 4;
    const int c4 = (idx & 15) * 4;
    const float4 v = *(const float4*)(in + (size_t)(k0 + r) * N + n0 + c4);
    t[r][c4 + 0] = v.x; t[r][c4 + 1] = v.y; t[r][c4 + 2] = v.z; t[r][c4 + 3] = v.w;
  }
  __syncthreads();
  for (int idx = tid; idx < 64 * 16; idx += 256) {
    const int a = idx >> 4;
    const int b4 = (idx & 15) * 4;
    ushort4 h, l;
#pragma unroll
    for (int q = 0; q < 4; ++q) {
      const float v = t[b4 + q][a];
      const unsigned short hu = f2bf(v);
      const unsigned short lu = f2bf(v - bf2f(hu));
      ((unsigned short*)&h)[q] = hu;
      ((unsigned short*)&l)[q] = lu;
    }
    *(ushort4*)(ohi + (size_t)(n0 + a) * K + k0 + b4) = h;
    *(ushort4*)(olo + (size_t)(n0 + a) * K + k0 + b4) = l;
  }
}

// ---------------------------------------------------------------------------
// Plain bf16 MFMA GEMM (m97 structure): C[M][ldc] = A[M][K] * Bt[N][K]^T.
// ---------------------------------------------------------------------------
#define BM 128
#define BN 128
#define BK 32

template <typename OT>
__global__ __launch_bounds__(256) void gemm_bf16_bt(const unsigned short* __restrict__ A,
                                                    const unsigned short* __restrict__ Bt,
                                                    OT* __restrict__ C,
                                                    int M, int N, int K, int ldc) {
  __shared__ unsigned short As[BM * BK];
  __shared__ unsigned short Bs[BN * BK];

  const int tid = threadIdx.x;
  const int lane = tid & 63;
  const int wave = tid >> 6;
  const int m0 = blockIdx.y * BM;
  const int n0 = blockIdx.x * BN;

  const int qm = (wave >> 1) * 64;
  const int qn = (wave & 1) * 64;
  const int l15 = lane & 15;
  const int quad = lane >> 4;

  const int st_row = lane >> 2;
  const int st_col = (lane & 3) * 8;

  f32x4 acc[4][4] = {};

  for (int k0 = 0; k0 < K; k0 += BK) {
#pragma unroll
    for (int p = 0; p < 2; ++p) {
      const int rb = p * 64 + wave * 16;
      gload16(A + (size_t)(m0 + rb + st_row) * K + k0 + st_col, &As[rb * BK]);
      gload16(Bt + (size_t)(n0 + rb + st_row) * K + k0 + st_col, &Bs[rb * BK]);
    }
    __syncthreads();

    s16x8 a[4], b[4];
#pragma unroll
    for (int i = 0; i < 4; ++i)
      a[i] = *(const s16x8*)&As[(qm + i * 16 + l15) * BK + quad * 8];
#pragma unroll
    for (int j = 0; j < 4; ++j)
      b[j] = *(const s16x8*)&Bs[(qn + j * 16 + l15) * BK + quad * 8];
#pragma unroll
    for (int i = 0; i < 4; ++i)
#pragma unroll
      for (int j = 0; j < 4; ++j)
        acc[i][j] = __builtin_amdgcn_mfma_f32_16x16x32_bf16(a[i], b[j], acc[i][j], 0, 0, 0);
    __syncthreads();
  }

#pragma unroll
  for (int i = 0; i < 4; ++i) {
    const int row_base = m0 + qm + i * 16 + quad * 4;
#pragma unroll
    for (int j = 0; j < 4; ++j) {
      const int col = n0 + qn + j * 16 + l15;
#pragma unroll
      for (int r = 0; r < 4; ++r) {
        if constexpr (sizeof(OT) == 2)
          C[(size_t)(row_base + r) * ldc + col] = (OT)f2bf(acc[i][j][r]);
        else
          C[(size_t)(row_base + r) * ldc + col] = acc[i][j][r];
      }
    }
  }
}

// ---------------------------------------------------------------------------
// bf16 MFMA GEMM with TRANSPOSED bf16 store: Ct[N][ldct] = (A * Bt^T)^T.
// ---------------------------------------------------------------------------
__global__ __launch_bounds__(256) void gemm_bf16_bt_vt(const unsigned short* __restrict__ A,
                                                       const unsigned short* __restrict__ Bt,
                                                       unsigned short* __restrict__ Ct,
                                                       int M, int N, int K, int ldct) {
  __shared__ unsigned short As[BM * BK];
  __shared__ unsigned short Bs[BN * BK];

  const int tid = threadIdx.x;
  const int lane = tid & 63;
  const int wave = tid >> 6;
  const int m0 = blockIdx.y * BM;
  const int n0 = blockIdx.x * BN;

  const int qm = (wave >> 1) * 64;
  const int qn = (wave & 1) * 64;
  const int l15 = lane & 15;
  const int quad = lane >> 4;

  const int st_row = lane >> 2;
  const int st_col = (lane & 3) * 8;

  f32x4 acc[4][4] = {};

  for (int k0 = 0; k0 < K; k0 += BK) {
#pragma unroll
    for (int p = 0; p < 2; ++p) {
      const int rb = p * 64 + wave * 16;
      gload16(A + (size_t)(m0 + rb + st_row) * K + k0 + st_col, &As[rb * BK]);
      gload16(Bt + (size_t)(n0 + rb + st_row) * K + k0 + st_col, &Bs[rb * BK]);
    }
    __syncthreads();

    s16x8 a[4], b[4];
#pragma unroll
    for (int i = 0; i < 4; ++i)
      a[i] = *(const s16x8*)&As[(qm + i * 16 + l15) * BK + quad * 8];
#pragma unroll
    for (int j = 0; j < 4; ++j)
      b[j] = *(const s16x8*)&Bs[(qn + j * 16 + l15) * BK + quad * 8];
#pragma unroll
    for (int i = 0; i < 4; ++i)
#pragma unroll
      for (int j = 0; j < 4; ++j)
        acc[i][j] = __builtin_amdgcn_mfma_f32_16x16x32_bf16(a[i], b[j], acc[i][j], 0, 0, 0);
    __syncthreads();
  }

  // transposed store: Ct[n][m], 4 consecutive m per lane -> 8B bf16 store
#pragma unroll
  for (int i = 0; i < 4; ++i) {
    const int row_base = m0 + qm + i * 16 + quad * 4;  // m
#pragma unroll
    for (int j = 0; j < 4; ++j) {
      const int col = n0 + qn + j * 16 + l15;          // n
      ushort4 u;
      u.x = f2bf(acc[i][j][0]); u.y = f2bf(acc[i][j][1]);
      u.z = f2bf(acc[i][j][2]); u.w = f2bf(acc[i][j][3]);
      *(ushort4*)(Ct + (size_t)col * ldct + row_base) = u;
    }
  }
}

// ---------------------------------------------------------------------------
// Split-precision bf16 MFMA GEMM: C = (Ahi+Alo) * (Bhi+Blo)^T, dropping lo*lo.
// ---------------------------------------------------------------------------
__global__ __launch_bounds__(256) void gemm_split_bt(const unsigned short* __restrict__ Ahi,
                                                     const unsigned short* __restrict__ Alo,
                                                     const unsigned short* __restrict__ Bhi,
                                                     const unsigned short* __restrict__ Blo,
                                                     float* __restrict__ C,
                                                     int M, int N, int K, int ldc) {
  __shared__ unsigned short AsH[BM * BK];
  __shared__ unsigned short AsL[BM * BK];
  __shared__ unsigned short BsH[BN * BK];
  __shared__ unsigned short BsL[BN * BK];

  const int tid = threadIdx.x;
  const int lane = tid & 63;
  const int wave = tid >> 6;
  const int m0 = blockIdx.y * BM;
  const int n0 = blockIdx.x * BN;

  const int qm = (wave >> 1) * 64;
  const int qn = (wave & 1) * 64;
  const int l15 = lane & 15;
  const int quad = lane >> 4;

  const int st_row = lane >> 2;
  const int st_col = (lane & 3) * 8;

  f32x4 acc[4][4] = {};

  for (int k0 = 0; k0 < K; k0 += BK) {
#pragma unroll
    for (int p = 0; p < 2; ++p) {
      const int rb = p * 64 + wave * 16;
      const size_t aoff = (size_t)(m0 + rb + st_row) * K + k0 + st_col;
      const size_t boff = (size_t)(n0 + rb + st_row) * K + k0 + st_col;
      gload16(Ahi + aoff, &AsH[rb * BK]);
      gload16(Alo + aoff, &AsL[rb * BK]);
      gload16(Bhi + boff, &BsH[rb * BK]);
      gload16(Blo + boff, &BsL[rb * BK]);
    }
    __syncthreads();

    s16x8 ah[4], al[4], bh[4], bl[4];
#pragma unroll
    for (int i = 0; i < 4; ++i) {
      const int ro = (qm + i * 16 + l15) * BK + quad * 8;
      ah[i] = *(const s16x8*)&AsH[ro];
      al[i] = *(const s16x8*)&AsL[ro];
    }
#pragma unroll
    for (int j = 0; j < 4; ++j) {
      const int ro = (qn + j * 16 + l15) * BK + quad * 8;
      bh[j] = *(const s16x8*)&BsH[ro];
      bl[j] = *(const s16x8*)&BsL[ro];
    }
#pragma unroll
    for (int i = 0; i < 4; ++i)
#pragma unroll
      for (int j = 0; j < 4; ++j) {
        acc[i][j] = __builtin_amdgcn_mfma_f32_16x16x32_bf16(ah[i], bh[j], acc[i][j], 0, 0, 0);
        acc[i][j] = __builtin_amdgcn_mfma_f32_16x16x32_bf16(ah[i], bl[j], acc[i][j], 0, 0, 0);
        acc[i][j] = __builtin_amdgcn_mfma_f32_16x16x32_bf16(al[i], bh[j], acc[i][j], 0, 0, 0);
      }
    __syncthreads();
  }

#pragma unroll
  for (int i = 0; i < 4; ++i) {
    const int row_base = m0 + qm + i * 16 + quad * 4;
#pragma unroll
    for (int j = 0; j < 4; ++j) {
      const int col = n0 + qn + j * 16 + l15;
#pragma unroll
      for (int r = 0; r < 4; ++r)
        C[(size_t)(row_base + r) * ldc + col] = acc[i][j][r];
    }
  }
}

// ---------------------------------------------------------------------------
// Fused RMSNorm + RoPE on packed fp32 QK [S][3072], emitting SPLIT bf16:
// q (pre-scaled by QK_SCALE) -> qh/ql [S][2048]; k -> kh/kl [S][1024].
// ---------------------------------------------------------------------------
__global__ __launch_bounds__(128) void rmsnorm_rope_split(const float* __restrict__ qk,
                                                          const float* __restrict__ cosb,
                                                          const float* __restrict__ sinb,
                                                          unsigned short* __restrict__ qh,
                                                          unsigned short* __restrict__ ql,
                                                          unsigned short* __restrict__ kh,
                                                          unsigned short* __restrict__ kl) {
  const int s = blockIdx.x;
  const int hh = blockIdx.y;
  const bool is_q = (hh < 16);
  const int col = is_q ? hh * HD : 2048 + (hh - 16) * HD;
  const int t = threadIdx.x;  // 0..127 = d

  const float* row = qk + (size_t)s * 3072 + col;
  const float v = row[t];

  __shared__ float sv[HD];
  __shared__ float red[HD];
  sv[t] = v;
  red[t] = v * v;
  __syncthreads();
#pragma unroll
  for (int off = 64; off > 0; off >>= 1) {
    if (t < off) red[t] += red[t + off];
    __syncthreads();
  }
  const float r = rsqrtf(red[0] / (float)HD + EPS);

  const float xn = v * r;
  const float other = sv[t ^ 64] * r;
  const float rot = (t < 64) ? -other : other;
  const float c = cosb[(size_t)s * HD + t];
  const float sn = sinb[(size_t)s * HD + t];
  float o = xn * c + rot * sn;
  if (is_q) o *= QK_SCALE;

  const unsigned short hu = f2bf(o);
  const unsigned short lu = f2bf(o - bf2f(hu));
  if (is_q) {
    qh[(size_t)s * 2048 + hh * HD + t] = hu;
    ql[(size_t)s * 2048 + hh * HD + t] = lu;
  } else {
    kh[(size_t)s * 1024 + (hh - 16) * HD + t] = hu;
    kl[(size_t)s * 1024 + (hh - 16) * HD + t] = lu;
  }
}

// ---------------------------------------------------------------------------
// Flash attention, MFMA, 2x2 wave partition + DMA staging + swizzled LDS.
// grid (S/64, NH) = 512 blocks, block 256. Wave (rg,kg): rg = 32-row group,
// kg = 32-key half. Each wave runs an INDEPENDENT online softmax over its
// key-half (no per-tile cross-wave traffic); (m,l,O) pairs merge once at the
// end through LDS. K/V staged via global_load_lds with XOR-swizzled layouts
// (chunk ^ row-low-bits) so unpadded rows still give ~2-way-free fragment
// reads. Per-wave per-tile LDS reads: 16KB (K hi/lo half) + 8KB (V half)
// + 2KB (P) = 26KB, vs 50KB in the 1x4 design. LDS 58KB -> 2 blocks/CU.
// ---------------------------------------------------------------------------
#define FA_N 64

__global__ __launch_bounds__(256) void attn_flash_mfma(const unsigned short* __restrict__ qh,
                                                       const unsigned short* __restrict__ ql,
                                                       const unsigned short* __restrict__ kh,
                                                       const unsigned short* __restrict__ kl,
                                                       const unsigned short* __restrict__ vt,
                                                       unsigned short* __restrict__ out) {
  const int h = blockIdx.y;
  const int kvh = h >> 1;
  const int m0 = blockIdx.x * 64;
  const int tid = threadIdx.x;
  const int lane = tid & 63;
  const int wave = tid >> 6;
  const int rg = wave >> 1;   // row group (32 q-rows)
  const int kg = wave & 1;    // key half (32 of 64 keys)
  const int l15 = lane & 15;
  const int quad = lane >> 4;

  // LDS: Kh [64][128] @0, Kl @16384, Vt [128][64] @32768, Pt 4x[32][40] @49152
  // (Kh/Kl/Vt rows unpadded, chunk-XOR-swizzled). Merge epilogue reuses
  // bytes 0..33280 after a barrier.
  __shared__ char smem[59392];
  unsigned short* Kh = (unsigned short*)(smem);
  unsigned short* Kl = (unsigned short*)(smem + 16384);
  unsigned short* Vt = (unsigned short*)(smem + 32768);
  unsigned short* Pt = (unsigned short*)(smem + 49152) + wave * 1280;  // [32][40]

  // ---- Q fragments in registers (A-layout), once ----
  s16x8 qah[2][4], qal[2][4];
#pragma unroll
  for (int rt = 0; rt < 2; ++rt) {
    const int qrow = m0 + rg * 32 + rt * 16 + l15;
#pragma unroll
    for (int ks = 0; ks < 4; ++ks) {
      const size_t off = (size_t)qrow * 2048 + h * HD + ks * 32 + quad * 8;
      qah[rt][ks] = *(const s16x8*)(qh + off);
      qal[rt][ks] = *(const s16x8*)(ql + off);
    }
  }

  // ---- staging address precompute (per-lane, swizzled) ----
  // K rows: 256B = 16 chunks of 16B; LDS slot chunk' = chunk ^ (row&15).
  int ksrc[4], kdst[4];
#pragma unroll
  for (int p = 0; p < 4; ++p) {
    const int row = wave * 16 + p * 4 + (lane >> 4);
    const int c = (lane & 15) ^ (row & 15);
    ksrc[p] = row * 1024 + kvh * HD + c * 8;       // shorts; + n0*1024 per tile
    kdst[p] = (wave * 16 + p * 4) * 128;           // shorts, wave-uniform
  }
  // Vt rows (d): 128B = 8 chunks of 16B; slot chunk' = chunk ^ (d&7).
  int vsrc[4], vdst[4];
#pragma unroll
  for (int p = 0; p < 4; ++p) {
    const int d = wave * 32 + p * 8 + (lane >> 3);
    const int c = (lane & 7) ^ (d & 7);
    vsrc[p] = (kvh * HD + d) * 2048 + c * 8;       // shorts; + n0 per tile
    vdst[p] = (wave * 32 + p * 8) * 64;            // shorts, wave-uniform
  }

  f32x4 O[2][8] = {};
  float m_i[2][4], l_i[2][4];
#pragma unroll
  for (int rt = 0; rt < 2; ++rt)
#pragma unroll
    for (int r = 0; r < 4; ++r) { m_i[rt][r] = -1e30f; l_i[rt][r] = 0.f; }

  for (int n0 = 0; n0 < S; n0 += FA_N) {
    __syncthreads();  // previous tile's fragment reads done
    // ---- DMA staging: K hi/lo (16 rows/wave) + Vt (32 d-rows/wave) ----
#pragma unroll
    for (int p = 0; p < 4; ++p) {
      gload16(kh + (size_t)n0 * 1024 + ksrc[p], Kh + kdst[p]);
      gload16(kl + (size_t)n0 * 1024 + ksrc[p], Kl + kdst[p]);
      gload16(vt + (size_t)n0 + vsrc[p], Vt + vdst[p]);
    }
    __syncthreads();  // vmcnt drained by barrier semantics

    // ---- S = Q K^T over this wave's 32-key half, split precision ----
    f32x4 sacc[2][2] = {};  // [rt][j]
#pragma unroll
    for (int ks = 0; ks < 4; ++ks) {
      s16x8 bh[2], bl[2];
#pragma unroll
      for (int j = 0; j < 2; ++j) {
        const int row = kg * 32 + j * 16 + l15;          // key (local to tile)
        const int cp = ((ks * 4 + quad) ^ l15) * 8;      // swizzled chunk
        const int ro = row * 128 + cp;
        bh[j] = *(const s16x8*)&Kh[ro];
        bl[j] = *(const s16x8*)&Kl[ro];
      }
#pragma unroll
      for (int rt = 0; rt < 2; ++rt)
#pragma unroll
        for (int j = 0; j < 2; ++j) {
          sacc[rt][j] = __builtin_amdgcn_mfma_f32_16x16x32_bf16(qah[rt][ks], bh[j], sacc[rt][j], 0, 0, 0);
          sacc[rt][j] = __builtin_amdgcn_mfma_f32_16x16x32_bf16(qah[rt][ks], bl[j], sacc[rt][j], 0, 0, 0);
          sacc[rt][j] = __builtin_amdgcn_mfma_f32_16x16x32_bf16(qal[rt][ks], bh[j], sacc[rt][j], 0, 0, 0);
        }
    }

    // ---- independent online softmax (rows quad*4+r, cols l15+16j) ----
#pragma unroll
    for (int rt = 0; rt < 2; ++rt) {
#pragma unroll
      for (int r = 0; r < 4; ++r) {
        float mt = fmaxf(sacc[rt][0][r], sacc[rt][1][r]);
        mt = fmaxf(mt, __shfl_xor(mt, 1));
        mt = fmaxf(mt, __shfl_xor(mt, 2));
        mt = fmaxf(mt, __shfl_xor(mt, 4));
        mt = fmaxf(mt, __shfl_xor(mt, 8));
        const float mnew = fmaxf(m_i[rt][r], mt);
        const float alpha = __expf(m_i[rt][r] - mnew);
        m_i[rt][r] = mnew;
        const float p0 = __expf(sacc[rt][0][r] - mnew);
        const float p1 = __expf(sacc[rt][1][r] - mnew);
        float ls = p0 + p1;
        ls += __shfl_xor(ls, 1);
        ls += __shfl_xor(ls, 2);
        ls += __shfl_xor(ls, 4);
        ls += __shfl_xor(ls, 8);
        l_i[rt][r] = l_i[rt][r] * alpha + ls;
#pragma unroll
        for (int jd = 0; jd < 8; ++jd) O[rt][jd][r] *= alpha;
        const int prow = rt * 16 + quad * 4 + r;
        Pt[prow * 40 + l15] = f2bf(p0);
        Pt[prow * 40 + 16 + l15] = f2bf(p1);
      }
    }
    // no barrier: Pt is per-wave private; DS ops within a wave are ordered.

    // ---- O += P V over this wave's 32 keys (K=32: one MFMA per tile) ----
    s16x8 pa[2];
#pragma unroll
    for (int rt = 0; rt < 2; ++rt)
      pa[rt] = *(const s16x8*)&Pt[(rt * 16 + l15) * 40 + quad * 8];
#pragma unroll
    for (int jd = 0; jd < 8; ++jd) {
      const int d = jd * 16 + l15;
      const int cp = ((kg * 4 + quad) ^ (d & 7)) * 8;
      const s16x8 vb = *(const s16x8*)&Vt[d * 64 + cp];
#pragma unroll
      for (int rt = 0; rt < 2; ++rt)
        O[rt][jd] = __builtin_amdgcn_mfma_f32_16x16x32_bf16(pa[rt], vb, O[rt][jd], 0, 0, 0);
    }
  }

  // ---- merge the two key-halves per row group, then store ----
  __syncthreads();  // all fragment reads done; reuse LDS
  float* Om = (float*)smem;                 // [2 rg][32 rows][128]
  float* ms = (float*)(smem + 32768);       // [2][32]
  float* ls2 = (float*)(smem + 33024);      // [2][32]

  if (kg == 1) {
#pragma unroll
    for (int rt = 0; rt < 2; ++rt)
#pragma unroll
      for (int r = 0; r < 4; ++r) {
        const int row = rt * 16 + quad * 4 + r;
        if (l15 == 0) {
          ms[rg * 32 + row] = m_i[rt][r];
          ls2[rg * 32 + row] = l_i[rt][r];
        }
#pragma unroll
        for (int jd = 0; jd < 8; ++jd)
          Om[(size_t)(rg * 32 + row) * 128 + jd * 16 + l15] = O[rt][jd][r];
      }
  }
  __syncthreads();
  if (kg == 0) {
#pragma unroll
    for (int rt = 0; rt < 2; ++rt)
#pragma unroll
      for (int r = 0; r < 4; ++r) {
        const int row = rt * 16 + quad * 4 + r;
        const float mB = ms[rg * 32 + row];
        const float lB = ls2[rg * 32 + row];
        const float mS = fmaxf(m_i[rt][r], mB);
        const float aA = __expf(m_i[rt][r] - mS);
        const float aB = __expf(mB - mS);
        const float inv = 1.f / (aA * l_i[rt][r] + aB * lB);
        const int grow = m0 + rg * 32 + row;
#pragma unroll
        for (int jd = 0; jd < 8; ++jd) {
          const float oB = Om[(size_t)(rg * 32 + row) * 128 + jd * 16 + l15];
          out[(size_t)grow * 2048 + h * HD + jd * 16 + l15] =
              f2bf((aA * O[rt][jd][r] + aB * oB) * inv);
        }
      }
  }
}

// ---------------------------------------------------------------------------
extern "C" void kernel_launch(void* const* d_in, const int* in_sizes, int n_in,
                              void* d_out, int out_size, void* d_ws, size_t ws_size,
                              hipStream_t stream) {
  const float* hidden = (const float*)d_in[0];  // [S][HID]
  const float* cosb   = (const float*)d_in[1];  // [S][HD]
  const float* sinb   = (const float*)d_in[2];  // [S][HD]
  const float* wq     = (const float*)d_in[3];  // [HID][2048]
  const float* wk     = (const float*)d_in[4];  // [HID][1024]
  const float* wv     = (const float*)d_in[5];  // [HID][1024]
  const float* wo     = (const float*)d_in[6];  // [2048][HID]
  float* out = (float*)d_out;                   // [S][HID]

  // Workspace map (72 MB, regions reused once dead):
  char* w = (char*)d_ws;
  float* qk_buf           = (float*)(w);                          //  0-24 MB fp32 [S][3072]
  unsigned short* wqkT_hi = (unsigned short*)(w + (24u << 20));   // 24-36 (dead after QK gemm)
  unsigned short* wqkT_lo = (unsigned short*)(w + (36u << 20));   // 36-48 (dead after QK gemm)
  unsigned short* hid_hi  = (unsigned short*)(w + (48u << 20));   // 48-56 (dead after V gemm)
  unsigned short* hid_lo  = (unsigned short*)(w + (56u << 20));   // 56-64 (dead after QK gemm)
  unsigned short* vt_b    = (unsigned short*)(w + (64u << 20));   // 64-68 V^T bf16 [1024][2048]
  unsigned short* wvT     = (unsigned short*)(w + (68u << 20));   // 68-72
  // reuse after QK gemm:
  unsigned short* q_hi    = (unsigned short*)(w + (24u << 20));   // 24-32 [S][2048]
  unsigned short* q_lo    = (unsigned short*)(w + (32u << 20));   // 32-40
  unsigned short* k_hi    = (unsigned short*)(w + (40u << 20));   // 40-44 [S][1024]
  unsigned short* k_lo    = (unsigned short*)(w + (44u << 20));   // 44-48
  // reuse after V gemm:
  unsigned short* woT     = (unsigned short*)(w + (48u << 20));   // 48-56 [2048][2048]
  unsigned short* a_b     = (unsigned short*)(w + (56u << 20));   // 56-64 [S][2048]

  dim3 blk(256);

  // prologue
  f32_to_bf16_split<<<dim3((S * HID / 4 + 255) / 256), blk, 0, stream>>>(hidden, hid_hi, hid_lo, S * HID / 4);
  transpose_to_bf16_split<<<dim3(32, 32), blk, 0, stream>>>(wq, wqkT_hi, wqkT_lo, HID, 2048);
  transpose_to_bf16_split<<<dim3(16, 32), blk, 0, stream>>>(wk, wqkT_hi + (size_t)2048 * 2048,
                                                            wqkT_lo + (size_t)2048 * 2048, HID, 1024);
  transpose_to_bf16<<<dim3(16, 32), blk, 0, stream>>>(wv, wvT, 2048, 1024);

  // QK projection (split precision) -> fp32 [S][3072]
  gemm_split_bt<<<dim3(3072 / BN, S / BM), blk, 0, stream>>>(hid_hi, hid_lo, wqkT_hi, wqkT_lo,
                                                             qk_buf, S, 3072, HID, 3072);

  // V projection -> transposed bf16 [1024][2048]
  gemm_bf16_bt_vt<<<dim3(1024 / BN, S / BM), blk, 0, stream>>>(hid_hi, wvT, vt_b, S, 1024, HID, 2048);

  // wo transpose into dead hid_hi region (after V gemm in stream order)
  transpose_to_bf16<<<dim3(32, 32), blk, 0, stream>>>(wo, woT, 2048, HID);

  // RMSNorm + RoPE -> split bf16 q/k (q pre-scaled)
  rmsnorm_rope_split<<<dim3(S, 24), dim3(128), 0, stream>>>(qk_buf, cosb, sinb, q_hi, q_lo, k_hi, k_lo);

  // MFMA flash attention -> bf16 [S][2048]
  attn_flash_mfma<<<dim3(S / 64, NH), blk, 0, stream>>>(q_hi, q_lo, k_hi, k_lo, vt_b, a_b);

  // output projection -> fp32 out
  gemm_bf16_bt<float><<<dim3(HID / BN, S / BM), blk, 0, stream>>>(a_b, woT, out, S, HID, 2048, HID);
}

// Round 8
// 463.476 us; speedup vs baseline: 1.2083x; 1.2083x over previous
//
#include <hip/hip_runtime.h>
#include <hip/hip_bf16.h>
#include <math.h>

// Problem constants
#define S 2048
#define HID 2048
#define NH 16
#define KVH 8
#define HD 128
#define EPS 1e-6f
#define QK_SCALE 11.313708498984760390f  // 1/SCALING = sqrt(128)

typedef __attribute__((ext_vector_type(8))) short s16x8;
typedef __attribute__((ext_vector_type(4))) float f32x4;

__device__ __forceinline__ unsigned short f2bf(float f) {
  __hip_bfloat16 h = __float2bfloat16(f);
  return *(unsigned short*)&h;
}
__device__ __forceinline__ float bf2f(unsigned short u) {
  unsigned int x = ((unsigned int)u) << 16;
  return __builtin_bit_cast(float, x);
}

__device__ __forceinline__ void gload16(const void* g, void* l) {
  __builtin_amdgcn_global_load_lds(
      (const __attribute__((address_space(1))) void*)g,
      (__attribute__((address_space(3))) void*)l, 16, 0, 0);
}

// ---------------------------------------------------------------------------
// fp32 -> split bf16 (hi + lo) elementwise.
// ---------------------------------------------------------------------------
__global__ __launch_bounds__(256) void f32_to_bf16_split(const float* __restrict__ in,
                                                         unsigned short* __restrict__ hi,
                                                         unsigned short* __restrict__ lo,
                                                         int n4) {
  const int i = blockIdx.x * 256 + threadIdx.x;
  if (i < n4) {
    const float4 v = *(const float4*)(in + (size_t)i * 4);
    ushort4 h, l;
    h.x = f2bf(v.x); l.x = f2bf(v.x - bf2f(h.x));
    h.y = f2bf(v.y); l.y = f2bf(v.y - bf2f(h.y));
    h.z = f2bf(v.z); l.z = f2bf(v.z - bf2f(h.z));
    h.w = f2bf(v.w); l.w = f2bf(v.w - bf2f(h.w));
    *(ushort4*)(hi + (size_t)i * 4) = h;
    *(ushort4*)(lo + (size_t)i * 4) = l;
  }
}

// ---------------------------------------------------------------------------
// Transpose fp32 [K][N] -> bf16 [N][K], plain.
// ---------------------------------------------------------------------------
__global__ __launch_bounds__(256) void transpose_to_bf16(const float* __restrict__ in,
                                                         unsigned short* __restrict__ out,
                                                         int K, int N) {
  __shared__ float t[64][65];
  const int n0 = blockIdx.x * 64;
  const int k0 = blockIdx.y * 64;
  const int tid = threadIdx.x;

  for (int idx = tid; idx < 64 * 16; idx += 256) {
    const int r = idx >> 4;
    const int c4 = (idx & 15) * 4;
    const float4 v = *(const float4*)(in + (size_t)(k0 + r) * N + n0 + c4);
    t[r][c4 + 0] = v.x; t[r][c4 + 1] = v.y; t[r][c4 + 2] = v.z; t[r][c4 + 3] = v.w;
  }
  __syncthreads();
  for (int idx = tid; idx < 64 * 16; idx += 256) {
    const int a = idx >> 4;
    const int b4 = (idx & 15) * 4;
    ushort4 u;
    u.x = f2bf(t[b4 + 0][a]); u.y = f2bf(t[b4 + 1][a]);
    u.z = f2bf(t[b4 + 2][a]); u.w = f2bf(t[b4 + 3][a]);
    *(ushort4*)(out + (size_t)(n0 + a) * K + k0 + b4) = u;
  }
}

// ---------------------------------------------------------------------------
// Transpose fp32 [K][N] -> split bf16 hi/lo [N][K].
// ---------------------------------------------------------------------------
__global__ __launch_bounds__(256) void transpose_to_bf16_split(const float* __restrict__ in,
                                                               unsigned short* __restrict__ ohi,
                                                               unsigned short* __restrict__ olo,
                                                               int K, int N) {
  __shared__ float t[64][65];
  const int n0 = blockIdx.x * 64;
  const int k0 = blockIdx.y * 64;
  const int tid = threadIdx.x;

  for (int idx = tid; idx < 64 * 16; idx += 256) {
    const int r = idx >> 4;
    const int c4 = (idx & 15) * 4;
    const float4 v = *(const float4*)(in + (size_t)(k0 + r) * N + n0 + c4);
    t[r][c4 + 0] = v.x; t[r][c4 + 1] = v.y; t[r][c4 + 2] = v.z; t[r][c4 + 3] = v.w;
  }
  __syncthreads();
  for (int idx = tid; idx < 64 * 16; idx += 256) {
    const int a = idx >> 4;
    const int b4 = (idx & 15) * 4;
    ushort4 h, l;
#pragma unroll
    for (int q = 0; q < 4; ++q) {
      const float v = t[b4 + q][a];
      const unsigned short hu = f2bf(v);
      const unsigned short lu = f2bf(v - bf2f(hu));
      ((unsigned short*)&h)[q] = hu;
      ((unsigned short*)&l)[q] = lu;
    }
    *(ushort4*)(ohi + (size_t)(n0 + a) * K + k0 + b4) = h;
    *(ushort4*)(olo + (size_t)(n0 + a) * K + k0 + b4) = l;
  }
}

// ---------------------------------------------------------------------------
// Plain bf16 MFMA GEMM (m97 structure): C[M][ldc] = A[M][K] * Bt[N][K]^T.
// ---------------------------------------------------------------------------
#define BM 128
#define BN 128
#define BK 32

template <typename OT>
__global__ __launch_bounds__(256) void gemm_bf16_bt(const unsigned short* __restrict__ A,
                                                    const unsigned short* __restrict__ Bt,
                                                    OT* __restrict__ C,
                                                    int M, int N, int K, int ldc) {
  __shared__ unsigned short As[BM * BK];
  __shared__ unsigned short Bs[BN * BK];

  const int tid = threadIdx.x;
  const int lane = tid & 63;
  const int wave = tid >> 6;
  const int m0 = blockIdx.y * BM;
  const int n0 = blockIdx.x * BN;

  const int qm = (wave >> 1) * 64;
  const int qn = (wave & 1) * 64;
  const int l15 = lane & 15;
  const int quad = lane >> 4;

  const int st_row = lane >> 2;
  const int st_col = (lane & 3) * 8;

  f32x4 acc[4][4] = {};

  for (int k0 = 0; k0 < K; k0 += BK) {
#pragma unroll
    for (int p = 0; p < 2; ++p) {
      const int rb = p * 64 + wave * 16;
      gload16(A + (size_t)(m0 + rb + st_row) * K + k0 + st_col, &As[rb * BK]);
      gload16(Bt + (size_t)(n0 + rb + st_row) * K + k0 + st_col, &Bs[rb * BK]);
    }
    __syncthreads();

    s16x8 a[4], b[4];
#pragma unroll
    for (int i = 0; i < 4; ++i)
      a[i] = *(const s16x8*)&As[(qm + i * 16 + l15) * BK + quad * 8];
#pragma unroll
    for (int j = 0; j < 4; ++j)
      b[j] = *(const s16x8*)&Bs[(qn + j * 16 + l15) * BK + quad * 8];
#pragma unroll
    for (int i = 0; i < 4; ++i)
#pragma unroll
      for (int j = 0; j < 4; ++j)
        acc[i][j] = __builtin_amdgcn_mfma_f32_16x16x32_bf16(a[i], b[j], acc[i][j], 0, 0, 0);
    __syncthreads();
  }

#pragma unroll
  for (int i = 0; i < 4; ++i) {
    const int row_base = m0 + qm + i * 16 + quad * 4;
#pragma unroll
    for (int j = 0; j < 4; ++j) {
      const int col = n0 + qn + j * 16 + l15;
#pragma unroll
      for (int r = 0; r < 4; ++r) {
        if constexpr (sizeof(OT) == 2)
          C[(size_t)(row_base + r) * ldc + col] = (OT)f2bf(acc[i][j][r]);
        else
          C[(size_t)(row_base + r) * ldc + col] = acc[i][j][r];
      }
    }
  }
}

// ---------------------------------------------------------------------------
// bf16 MFMA GEMM with TRANSPOSED bf16 store: Ct[N][ldct] = (A * Bt^T)^T.
// ---------------------------------------------------------------------------
__global__ __launch_bounds__(256) void gemm_bf16_bt_vt(const unsigned short* __restrict__ A,
                                                       const unsigned short* __restrict__ Bt,
                                                       unsigned short* __restrict__ Ct,
                                                       int M, int N, int K, int ldct) {
  __shared__ unsigned short As[BM * BK];
  __shared__ unsigned short Bs[BN * BK];

  const int tid = threadIdx.x;
  const int lane = tid & 63;
  const int wave = tid >> 6;
  const int m0 = blockIdx.y * BM;
  const int n0 = blockIdx.x * BN;

  const int qm = (wave >> 1) * 64;
  const int qn = (wave & 1) * 64;
  const int l15 = lane & 15;
  const int quad = lane >> 4;

  const int st_row = lane >> 2;
  const int st_col = (lane & 3) * 8;

  f32x4 acc[4][4] = {};

  for (int k0 = 0; k0 < K; k0 += BK) {
#pragma unroll
    for (int p = 0; p < 2; ++p) {
      const int rb = p * 64 + wave * 16;
      gload16(A + (size_t)(m0 + rb + st_row) * K + k0 + st_col, &As[rb * BK]);
      gload16(Bt + (size_t)(n0 + rb + st_row) * K + k0 + st_col, &Bs[rb * BK]);
    }
    __syncthreads();

    s16x8 a[4], b[4];
#pragma unroll
    for (int i = 0; i < 4; ++i)
      a[i] = *(const s16x8*)&As[(qm + i * 16 + l15) * BK + quad * 8];
#pragma unroll
    for (int j = 0; j < 4; ++j)
      b[j] = *(const s16x8*)&Bs[(qn + j * 16 + l15) * BK + quad * 8];
#pragma unroll
    for (int i = 0; i < 4; ++i)
#pragma unroll
      for (int j = 0; j < 4; ++j)
        acc[i][j] = __builtin_amdgcn_mfma_f32_16x16x32_bf16(a[i], b[j], acc[i][j], 0, 0, 0);
    __syncthreads();
  }

  // transposed store: Ct[n][m], 4 consecutive m per lane -> 8B bf16 store
#pragma unroll
  for (int i = 0; i < 4; ++i) {
    const int row_base = m0 + qm + i * 16 + quad * 4;  // m
#pragma unroll
    for (int j = 0; j < 4; ++j) {
      const int col = n0 + qn + j * 16 + l15;          // n
      ushort4 u;
      u.x = f2bf(acc[i][j][0]); u.y = f2bf(acc[i][j][1]);
      u.z = f2bf(acc[i][j][2]); u.w = f2bf(acc[i][j][3]);
      *(ushort4*)(Ct + (size_t)col * ldct + row_base) = u;
    }
  }
}

// ---------------------------------------------------------------------------
// Split-precision bf16 MFMA GEMM: C = (Ahi+Alo) * (Bhi+Blo)^T, dropping lo*lo.
// ---------------------------------------------------------------------------
__global__ __launch_bounds__(256) void gemm_split_bt(const unsigned short* __restrict__ Ahi,
                                                     const unsigned short* __restrict__ Alo,
                                                     const unsigned short* __restrict__ Bhi,
                                                     const unsigned short* __restrict__ Blo,
                                                     float* __restrict__ C,
                                                     int M, int N, int K, int ldc) {
  __shared__ unsigned short AsH[BM * BK];
  __shared__ unsigned short AsL[BM * BK];
  __shared__ unsigned short BsH[BN * BK];
  __shared__ unsigned short BsL[BN * BK];

  const int tid = threadIdx.x;
  const int lane = tid & 63;
  const int wave = tid >> 6;
  const int m0 = blockIdx.y * BM;
  const int n0 = blockIdx.x * BN;

  const int qm = (wave >> 1) * 64;
  const int qn = (wave & 1) * 64;
  const int l15 = lane & 15;
  const int quad = lane >> 4;

  const int st_row = lane >> 2;
  const int st_col = (lane & 3) * 8;

  f32x4 acc[4][4] = {};

  for (int k0 = 0; k0 < K; k0 += BK) {
#pragma unroll
    for (int p = 0; p < 2; ++p) {
      const int rb = p * 64 + wave * 16;
      const size_t aoff = (size_t)(m0 + rb + st_row) * K + k0 + st_col;
      const size_t boff = (size_t)(n0 + rb + st_row) * K + k0 + st_col;
      gload16(Ahi + aoff, &AsH[rb * BK]);
      gload16(Alo + aoff, &AsL[rb * BK]);
      gload16(Bhi + boff, &BsH[rb * BK]);
      gload16(Blo + boff, &BsL[rb * BK]);
    }
    __syncthreads();

    s16x8 ah[4], al[4], bh[4], bl[4];
#pragma unroll
    for (int i = 0; i < 4; ++i) {
      const int ro = (qm + i * 16 + l15) * BK + quad * 8;
      ah[i] = *(const s16x8*)&AsH[ro];
      al[i] = *(const s16x8*)&AsL[ro];
    }
#pragma unroll
    for (int j = 0; j < 4; ++j) {
      const int ro = (qn + j * 16 + l15) * BK + quad * 8;
      bh[j] = *(const s16x8*)&BsH[ro];
      bl[j] = *(const s16x8*)&BsL[ro];
    }
#pragma unroll
    for (int i = 0; i < 4; ++i)
#pragma unroll
      for (int j = 0; j < 4; ++j) {
        acc[i][j] = __builtin_amdgcn_mfma_f32_16x16x32_bf16(ah[i], bh[j], acc[i][j], 0, 0, 0);
        acc[i][j] = __builtin_amdgcn_mfma_f32_16x16x32_bf16(ah[i], bl[j], acc[i][j], 0, 0, 0);
        acc[i][j] = __builtin_amdgcn_mfma_f32_16x16x32_bf16(al[i], bh[j], acc[i][j], 0, 0, 0);
      }
    __syncthreads();
  }

#pragma unroll
  for (int i = 0; i < 4; ++i) {
    const int row_base = m0 + qm + i * 16 + quad * 4;
#pragma unroll
    for (int j = 0; j < 4; ++j) {
      const int col = n0 + qn + j * 16 + l15;
#pragma unroll
      for (int r = 0; r < 4; ++r)
        C[(size_t)(row_base + r) * ldc + col] = acc[i][j][r];
    }
  }
}

// ---------------------------------------------------------------------------
// Fused RMSNorm + RoPE on packed fp32 QK [S][3072], emitting SPLIT bf16:
// q (pre-scaled by QK_SCALE) -> qh/ql [S][2048]; k -> kh/kl [S][1024].
// ---------------------------------------------------------------------------
__global__ __launch_bounds__(128) void rmsnorm_rope_split(const float* __restrict__ qk,
                                                          const float* __restrict__ cosb,
                                                          const float* __restrict__ sinb,
                                                          unsigned short* __restrict__ qh,
                                                          unsigned short* __restrict__ ql,
                                                          unsigned short* __restrict__ kh,
                                                          unsigned short* __restrict__ kl) {
  const int s = blockIdx.x;
  const int hh = blockIdx.y;
  const bool is_q = (hh < 16);
  const int col = is_q ? hh * HD : 2048 + (hh - 16) * HD;
  const int t = threadIdx.x;  // 0..127 = d

  const float* row = qk + (size_t)s * 3072 + col;
  const float v = row[t];

  __shared__ float sv[HD];
  __shared__ float red[HD];
  sv[t] = v;
  red[t] = v * v;
  __syncthreads();
#pragma unroll
  for (int off = 64; off > 0; off >>= 1) {
    if (t < off) red[t] += red[t + off];
    __syncthreads();
  }
  const float r = rsqrtf(red[0] / (float)HD + EPS);

  const float xn = v * r;
  const float other = sv[t ^ 64] * r;
  const float rot = (t < 64) ? -other : other;
  const float c = cosb[(size_t)s * HD + t];
  const float sn = sinb[(size_t)s * HD + t];
  float o = xn * c + rot * sn;
  if (is_q) o *= QK_SCALE;

  const unsigned short hu = f2bf(o);
  const unsigned short lu = f2bf(o - bf2f(hu));
  if (is_q) {
    qh[(size_t)s * 2048 + hh * HD + t] = hu;
    ql[(size_t)s * 2048 + hh * HD + t] = lu;
  } else {
    kh[(size_t)s * 1024 + (hh - 16) * HD + t] = hu;
    kl[(size_t)s * 1024 + (hh - 16) * HD + t] = lu;
  }
}

// ---------------------------------------------------------------------------
// Flash attention, MFMA, 2x2 wave partition + DMA staging + swizzled LDS.
// Same structure as round 7 BUT __launch_bounds__(256, 2): cap total
// VGPR+AGPR at 256/wave so 2 blocks/CU co-reside (round 7's 152 VGPR +
// ~110 AGPR > 256 forced 1 wave/SIMD -> occupancy collapse). Staging
// addresses recomputed per tile (saves ~16 persistent VGPRs).
// ---------------------------------------------------------------------------
#define FA_N 64

__global__ __launch_bounds__(256, 2) void attn_flash_mfma(const unsigned short* __restrict__ qh,
                                                          const unsigned short* __restrict__ ql,
                                                          const unsigned short* __restrict__ kh,
                                                          const unsigned short* __restrict__ kl,
                                                          const unsigned short* __restrict__ vt,
                                                          unsigned short* __restrict__ out) {
  const int h = blockIdx.y;
  const int kvh = h >> 1;
  const int m0 = blockIdx.x * 64;
  const int tid = threadIdx.x;
  const int lane = tid & 63;
  const int wave = tid >> 6;
  const int rg = wave >> 1;   // row group (32 q-rows)
  const int kg = wave & 1;    // key half (32 of 64 keys)
  const int l15 = lane & 15;
  const int quad = lane >> 4;

  // LDS: Kh [64][128] @0, Kl @16384, Vt [128][64] @32768, Pt 4x[32][40] @49152
  // (rows unpadded, chunk-XOR-swizzled). Merge epilogue reuses 0..33280.
  __shared__ char smem[59392];
  unsigned short* Kh = (unsigned short*)(smem);
  unsigned short* Kl = (unsigned short*)(smem + 16384);
  unsigned short* Vt = (unsigned short*)(smem + 32768);
  unsigned short* Pt = (unsigned short*)(smem + 49152) + wave * 1280;  // [32][40]

  // ---- Q fragments in registers (A-layout), once ----
  s16x8 qah[2][4], qal[2][4];
#pragma unroll
  for (int rt = 0; rt < 2; ++rt) {
    const int qrow = m0 + rg * 32 + rt * 16 + l15;
#pragma unroll
    for (int ks = 0; ks < 4; ++ks) {
      const size_t off = (size_t)qrow * 2048 + h * HD + ks * 32 + quad * 8;
      qah[rt][ks] = *(const s16x8*)(qh + off);
      qal[rt][ks] = *(const s16x8*)(ql + off);
    }
  }

  f32x4 O[2][8] = {};
  float m_i[2][4], l_i[2][4];
#pragma unroll
  for (int rt = 0; rt < 2; ++rt)
#pragma unroll
    for (int r = 0; r < 4; ++r) { m_i[rt][r] = -1e30f; l_i[rt][r] = 0.f; }

  for (int n0 = 0; n0 < S; n0 += FA_N) {
    __syncthreads();  // previous tile's fragment reads done
    // ---- DMA staging (addresses recomputed; swizzle chunk ^ row-low-bits) --
#pragma unroll
    for (int p = 0; p < 4; ++p) {
      // K: row covers 256B = 16 chunks of 16B
      const int krow = wave * 16 + p * 4 + (lane >> 4);
      const int kc = (lane & 15) ^ (krow & 15);
      const size_t ksrc = (size_t)(n0 + krow) * 1024 + kvh * HD + kc * 8;
      const int kdst = (wave * 16 + p * 4) * 128;  // wave-uniform
      gload16(kh + ksrc, Kh + kdst);
      gload16(kl + ksrc, Kl + kdst);
      // Vt: d-row covers 128B = 8 chunks of 16B
      const int d = wave * 32 + p * 8 + (lane >> 3);
      const int vc = (lane & 7) ^ (d & 7);
      const size_t vsrc = (size_t)(kvh * HD + d) * 2048 + n0 + vc * 8;
      const int vdst = (wave * 32 + p * 8) * 64;   // wave-uniform
      gload16(vt + vsrc, Vt + vdst);
    }
    __syncthreads();  // vmcnt drained by barrier semantics

    // ---- S = Q K^T over this wave's 32-key half, split precision ----
    f32x4 sacc[2][2] = {};  // [rt][j]
#pragma unroll
    for (int ks = 0; ks < 4; ++ks) {
      s16x8 bh[2], bl[2];
#pragma unroll
      for (int j = 0; j < 2; ++j) {
        const int row = kg * 32 + j * 16 + l15;          // key (local to tile)
        const int cp = ((ks * 4 + quad) ^ l15) * 8;      // swizzled chunk
        const int ro = row * 128 + cp;
        bh[j] = *(const s16x8*)&Kh[ro];
        bl[j] = *(const s16x8*)&Kl[ro];
      }
#pragma unroll
      for (int rt = 0; rt < 2; ++rt)
#pragma unroll
        for (int j = 0; j < 2; ++j) {
          sacc[rt][j] = __builtin_amdgcn_mfma_f32_16x16x32_bf16(qah[rt][ks], bh[j], sacc[rt][j], 0, 0, 0);
          sacc[rt][j] = __builtin_amdgcn_mfma_f32_16x16x32_bf16(qah[rt][ks], bl[j], sacc[rt][j], 0, 0, 0);
          sacc[rt][j] = __builtin_amdgcn_mfma_f32_16x16x32_bf16(qal[rt][ks], bh[j], sacc[rt][j], 0, 0, 0);
        }
    }

    // ---- independent online softmax (rows quad*4+r, cols l15+16j) ----
#pragma unroll
    for (int rt = 0; rt < 2; ++rt) {
#pragma unroll
      for (int r = 0; r < 4; ++r) {
        float mt = fmaxf(sacc[rt][0][r], sacc[rt][1][r]);
        mt = fmaxf(mt, __shfl_xor(mt, 1));
        mt = fmaxf(mt, __shfl_xor(mt, 2));
        mt = fmaxf(mt, __shfl_xor(mt, 4));
        mt = fmaxf(mt, __shfl_xor(mt, 8));
        const float mnew = fmaxf(m_i[rt][r], mt);
        const float alpha = __expf(m_i[rt][r] - mnew);
        m_i[rt][r] = mnew;
        const float p0 = __expf(sacc[rt][0][r] - mnew);
        const float p1 = __expf(sacc[rt][1][r] - mnew);
        float ls = p0 + p1;
        ls += __shfl_xor(ls, 1);
        ls += __shfl_xor(ls, 2);
        ls += __shfl_xor(ls, 4);
        ls += __shfl_xor(ls, 8);
        l_i[rt][r] = l_i[rt][r] * alpha + ls;
#pragma unroll
        for (int jd = 0; jd < 8; ++jd) O[rt][jd][r] *= alpha;
        const int prow = rt * 16 + quad * 4 + r;
        Pt[prow * 40 + l15] = f2bf(p0);
        Pt[prow * 40 + 16 + l15] = f2bf(p1);
      }
    }
    // no barrier: Pt is per-wave private; DS ops within a wave are ordered.

    // ---- O += P V over this wave's 32 keys (K=32: one MFMA per tile) ----
    s16x8 pa[2];
#pragma unroll
    for (int rt = 0; rt < 2; ++rt)
      pa[rt] = *(const s16x8*)&Pt[(rt * 16 + l15) * 40 + quad * 8];
#pragma unroll
    for (int jd = 0; jd < 8; ++jd) {
      const int d = jd * 16 + l15;
      const int cp = ((kg * 4 + quad) ^ (d & 7)) * 8;
      const s16x8 vb = *(const s16x8*)&Vt[d * 64 + cp];
#pragma unroll
      for (int rt = 0; rt < 2; ++rt)
        O[rt][jd] = __builtin_amdgcn_mfma_f32_16x16x32_bf16(pa[rt], vb, O[rt][jd], 0, 0, 0);
    }
  }

  // ---- merge the two key-halves per row group, then store ----
  __syncthreads();  // all fragment reads done; reuse LDS
  float* Om = (float*)smem;                 // [2 rg][32 rows][128]
  float* ms = (float*)(smem + 32768);       // [2][32]
  float* ls2 = (float*)(smem + 33024);      // [2][32]

  if (kg == 1) {
#pragma unroll
    for (int rt = 0; rt < 2; ++rt)
#pragma unroll
      for (int r = 0; r < 4; ++r) {
        const int row = rt * 16 + quad * 4 + r;
        if (l15 == 0) {
          ms[rg * 32 + row] = m_i[rt][r];
          ls2[rg * 32 + row] = l_i[rt][r];
        }
#pragma unroll
        for (int jd = 0; jd < 8; ++jd)
          Om[(size_t)(rg * 32 + row) * 128 + jd * 16 + l15] = O[rt][jd][r];
      }
  }
  __syncthreads();
  if (kg == 0) {
#pragma unroll
    for (int rt = 0; rt < 2; ++rt)
#pragma unroll
      for (int r = 0; r < 4; ++r) {
        const int row = rt * 16 + quad * 4 + r;
        const float mB = ms[rg * 32 + row];
        const float lB = ls2[rg * 32 + row];
        const float mS = fmaxf(m_i[rt][r], mB);
        const float aA = __expf(m_i[rt][r] - mS);
        const float aB = __expf(mB - mS);
        const float inv = 1.f / (aA * l_i[rt][r] + aB * lB);
        const int grow = m0 + rg * 32 + row;
#pragma unroll
        for (int jd = 0; jd < 8; ++jd) {
          const float oB = Om[(size_t)(rg * 32 + row) * 128 + jd * 16 + l15];
          out[(size_t)grow * 2048 + h * HD + jd * 16 + l15] =
              f2bf((aA * O[rt][jd][r] + aB * oB) * inv);
        }
      }
  }
}

// ---------------------------------------------------------------------------
extern "C" void kernel_launch(void* const* d_in, const int* in_sizes, int n_in,
                              void* d_out, int out_size, void* d_ws, size_t ws_size,
                              hipStream_t stream) {
  const float* hidden = (const float*)d_in[0];  // [S][HID]
  const float* cosb   = (const float*)d_in[1];  // [S][HD]
  const float* sinb   = (const float*)d_in[2];  // [S][HD]
  const float* wq     = (const float*)d_in[3];  // [HID][2048]
  const float* wk     = (const float*)d_in[4];  // [HID][1024]
  const float* wv     = (const float*)d_in[5];  // [HID][1024]
  const float* wo     = (const float*)d_in[6];  // [2048][HID]
  float* out = (float*)d_out;                   // [S][HID]

  // Workspace map (72 MB, regions reused once dead):
  char* w = (char*)d_ws;
  float* qk_buf           = (float*)(w);                          //  0-24 MB fp32 [S][3072]
  unsigned short* wqkT_hi = (unsigned short*)(w + (24u << 20));   // 24-36 (dead after QK gemm)
  unsigned short* wqkT_lo = (unsigned short*)(w + (36u << 20));   // 36-48 (dead after QK gemm)
  unsigned short* hid_hi  = (unsigned short*)(w + (48u << 20));   // 48-56 (dead after V gemm)
  unsigned short* hid_lo  = (unsigned short*)(w + (56u << 20));   // 56-64 (dead after QK gemm)
  unsigned short* vt_b    = (unsigned short*)(w + (64u << 20));   // 64-68 V^T bf16 [1024][2048]
  unsigned short* wvT     = (unsigned short*)(w + (68u << 20));   // 68-72
  // reuse after QK gemm:
  unsigned short* q_hi    = (unsigned short*)(w + (24u << 20));   // 24-32 [S][2048]
  unsigned short* q_lo    = (unsigned short*)(w + (32u << 20));   // 32-40
  unsigned short* k_hi    = (unsigned short*)(w + (40u << 20));   // 40-44 [S][1024]
  unsigned short* k_lo    = (unsigned short*)(w + (44u << 20));   // 44-48
  // reuse after V gemm:
  unsigned short* woT     = (unsigned short*)(w + (48u << 20));   // 48-56 [2048][2048]
  unsigned short* a_b     = (unsigned short*)(w + (56u << 20));   // 56-64 [S][2048]

  dim3 blk(256);

  // prologue
  f32_to_bf16_split<<<dim3((S * HID / 4 + 255) / 256), blk, 0, stream>>>(hidden, hid_hi, hid_lo, S * HID / 4);
  transpose_to_bf16_split<<<dim3(32, 32), blk, 0, stream>>>(wq, wqkT_hi, wqkT_lo, HID, 2048);
  transpose_to_bf16_split<<<dim3(16, 32), blk, 0, stream>>>(wk, wqkT_hi + (size_t)2048 * 2048,
                                                            wqkT_lo + (size_t)2048 * 2048, HID, 1024);
  transpose_to_bf16<<<dim3(16, 32), blk, 0, stream>>>(wv, wvT, 2048, 1024);

  // QK projection (split precision) -> fp32 [S][3072]
  gemm_split_bt<<<dim3(3072 / BN, S / BM), blk, 0, stream>>>(hid_hi, hid_lo, wqkT_hi, wqkT_lo,
                                                             qk_buf, S, 3072, HID, 3072);

  // V projection -> transposed bf16 [1024][2048]
  gemm_bf16_bt_vt<<<dim3(1024 / BN, S / BM), blk, 0, stream>>>(hid_hi, wvT, vt_b, S, 1024, HID, 2048);

  // wo transpose into dead hid_hi region (after V gemm in stream order)
  transpose_to_bf16<<<dim3(32, 32), blk, 0, stream>>>(wo, woT, 2048, HID);

  // RMSNorm + RoPE -> split bf16 q/k (q pre-scaled)
  rmsnorm_rope_split<<<dim3(S, 24), dim3(128), 0, stream>>>(qk_buf, cosb, sinb, q_hi, q_lo, k_hi, k_lo);

  // MFMA flash attention -> bf16 [S][2048]
  attn_flash_mfma<<<dim3(S / 64, NH), blk, 0, stream>>>(q_hi, q_lo, k_hi, k_lo, vt_b, a_b);

  // output projection -> fp32 out
  gemm_bf16_bt<float><<<dim3(HID / BN, S / BM), blk, 0, stream>>>(a_b, woT, out, S, HID, 2048, HID);
}

// Round 9
// 418.769 us; speedup vs baseline: 1.3373x; 1.1068x over previous
//
#include <hip/hip_runtime.h>
#include <hip/hip_bf16.h>
#include <math.h>

// Problem constants
#define S 2048
#define HID 2048
#define NH 16
#define KVH 8
#define HD 128
#define EPS 1e-6f
#define QK_SCALE 11.313708498984760390f  // 1/SCALING = sqrt(128)

typedef __attribute__((ext_vector_type(8))) short s16x8;
typedef __attribute__((ext_vector_type(4))) float f32x4;

__device__ __forceinline__ unsigned short f2bf(float f) {
  __hip_bfloat16 h = __float2bfloat16(f);
  return *(unsigned short*)&h;
}
__device__ __forceinline__ float bf2f(unsigned short u) {
  unsigned int x = ((unsigned int)u) << 16;
  return __builtin_bit_cast(float, x);
}

__device__ __forceinline__ void gload16(const void* g, void* l) {
  __builtin_amdgcn_global_load_lds(
      (const __attribute__((address_space(1))) void*)g,
      (__attribute__((address_space(3))) void*)l, 16, 0, 0);
}

// ---------------------------------------------------------------------------
// fp32 -> split bf16 (hi + lo) elementwise.
// ---------------------------------------------------------------------------
__global__ __launch_bounds__(256) void f32_to_bf16_split(const float* __restrict__ in,
                                                         unsigned short* __restrict__ hi,
                                                         unsigned short* __restrict__ lo,
                                                         int n4) {
  const int i = blockIdx.x * 256 + threadIdx.x;
  if (i < n4) {
    const float4 v = *(const float4*)(in + (size_t)i * 4);
    ushort4 h, l;
    h.x = f2bf(v.x); l.x = f2bf(v.x - bf2f(h.x));
    h.y = f2bf(v.y); l.y = f2bf(v.y - bf2f(h.y));
    h.z = f2bf(v.z); l.z = f2bf(v.z - bf2f(h.z));
    h.w = f2bf(v.w); l.w = f2bf(v.w - bf2f(h.w));
    *(ushort4*)(hi + (size_t)i * 4) = h;
    *(ushort4*)(lo + (size_t)i * 4) = l;
  }
}

// ---------------------------------------------------------------------------
// Transpose fp32 [K][N] -> bf16 [N][K], plain.
// ---------------------------------------------------------------------------
__global__ __launch_bounds__(256) void transpose_to_bf16(const float* __restrict__ in,
                                                         unsigned short* __restrict__ out,
                                                         int K, int N) {
  __shared__ float t[64][65];
  const int n0 = blockIdx.x * 64;
  const int k0 = blockIdx.y * 64;
  const int tid = threadIdx.x;

  for (int idx = tid; idx < 64 * 16; idx += 256) {
    const int r = idx >> 4;
    const int c4 = (idx & 15) * 4;
    const float4 v = *(const float4*)(in + (size_t)(k0 + r) * N + n0 + c4);
    t[r][c4 + 0] = v.x; t[r][c4 + 1] = v.y; t[r][c4 + 2] = v.z; t[r][c4 + 3] = v.w;
  }
  __syncthreads();
  for (int idx = tid; idx < 64 * 16; idx += 256) {
    const int a = idx >> 4;
    const int b4 = (idx & 15) * 4;
    ushort4 u;
    u.x = f2bf(t[b4 + 0][a]); u.y = f2bf(t[b4 + 1][a]);
    u.z = f2bf(t[b4 + 2][a]); u.w = f2bf(t[b4 + 3][a]);
    *(ushort4*)(out + (size_t)(n0 + a) * K + k0 + b4) = u;
  }
}

// ---------------------------------------------------------------------------
// Transpose fp32 [K][N] -> split bf16 hi/lo [N][K].
// ---------------------------------------------------------------------------
__global__ __launch_bounds__(256) void transpose_to_bf16_split(const float* __restrict__ in,
                                                               unsigned short* __restrict__ ohi,
                                                               unsigned short* __restrict__ olo,
                                                               int K, int N) {
  __shared__ float t[64][65];
  const int n0 = blockIdx.x * 64;
  const int k0 = blockIdx.y * 64;
  const int tid = threadIdx.x;

  for (int idx = tid; idx < 64 * 16; idx += 256) {
    const int r = idx >> 4;
    const int c4 = (idx & 15) * 4;
    const float4 v = *(const float4*)(in + (size_t)(k0 + r) * N + n0 + c4);
    t[r][c4 + 0] = v.x; t[r][c4 + 1] = v.y; t[r][c4 + 2] = v.z; t[r][c4 + 3] = v.w;
  }
  __syncthreads();
  for (int idx = tid; idx < 64 * 16; idx += 256) {
    const int a = idx >> 4;
    const int b4 = (idx & 15) * 4;
    ushort4 h, l;
#pragma unroll
    for (int q = 0; q < 4; ++q) {
      const float v = t[b4 + q][a];
      const unsigned short hu = f2bf(v);
      const unsigned short lu = f2bf(v - bf2f(hu));
      ((unsigned short*)&h)[q] = hu;
      ((unsigned short*)&l)[q] = lu;
    }
    *(ushort4*)(ohi + (size_t)(n0 + a) * K + k0 + b4) = h;
    *(ushort4*)(olo + (size_t)(n0 + a) * K + k0 + b4) = l;
  }
}

// ---------------------------------------------------------------------------
// Plain bf16 MFMA GEMM (m97 structure): C[M][ldc] = A[M][K] * Bt[N][K]^T.
// 128x128 tile.
// ---------------------------------------------------------------------------
#define BM 128
#define BN 128
#define BK 32

template <typename OT>
__global__ __launch_bounds__(256) void gemm_bf16_bt(const unsigned short* __restrict__ A,
                                                    const unsigned short* __restrict__ Bt,
                                                    OT* __restrict__ C,
                                                    int M, int N, int K, int ldc) {
  __shared__ unsigned short As[BM * BK];
  __shared__ unsigned short Bs[BN * BK];

  const int tid = threadIdx.x;
  const int lane = tid & 63;
  const int wave = tid >> 6;
  const int m0 = blockIdx.y * BM;
  const int n0 = blockIdx.x * BN;

  const int qm = (wave >> 1) * 64;
  const int qn = (wave & 1) * 64;
  const int l15 = lane & 15;
  const int quad = lane >> 4;

  const int st_row = lane >> 2;
  const int st_col = (lane & 3) * 8;

  f32x4 acc[4][4] = {};

  for (int k0 = 0; k0 < K; k0 += BK) {
#pragma unroll
    for (int p = 0; p < 2; ++p) {
      const int rb = p * 64 + wave * 16;
      gload16(A + (size_t)(m0 + rb + st_row) * K + k0 + st_col, &As[rb * BK]);
      gload16(Bt + (size_t)(n0 + rb + st_row) * K + k0 + st_col, &Bs[rb * BK]);
    }
    __syncthreads();

    s16x8 a[4], b[4];
#pragma unroll
    for (int i = 0; i < 4; ++i)
      a[i] = *(const s16x8*)&As[(qm + i * 16 + l15) * BK + quad * 8];
#pragma unroll
    for (int j = 0; j < 4; ++j)
      b[j] = *(const s16x8*)&Bs[(qn + j * 16 + l15) * BK + quad * 8];
#pragma unroll
    for (int i = 0; i < 4; ++i)
#pragma unroll
      for (int j = 0; j < 4; ++j)
        acc[i][j] = __builtin_amdgcn_mfma_f32_16x16x32_bf16(a[i], b[j], acc[i][j], 0, 0, 0);
    __syncthreads();
  }

#pragma unroll
  for (int i = 0; i < 4; ++i) {
    const int row_base = m0 + qm + i * 16 + quad * 4;
#pragma unroll
    for (int j = 0; j < 4; ++j) {
      const int col = n0 + qn + j * 16 + l15;
#pragma unroll
      for (int r = 0; r < 4; ++r) {
        if constexpr (sizeof(OT) == 2)
          C[(size_t)(row_base + r) * ldc + col] = (OT)f2bf(acc[i][j][r]);
        else
          C[(size_t)(row_base + r) * ldc + col] = acc[i][j][r];
      }
    }
  }
}

// ---------------------------------------------------------------------------
// 128x64-tile bf16 MFMA GEMM for grid-starved shapes (V proj, wo proj).
// MODE 0: float C store. MODE 1: transposed bf16 store Ct[n][ldct]+m.
// 256 threads, 4 waves in 2x2 quadrants of 64x32.
// ---------------------------------------------------------------------------
template <int MODE, typename OT>
__global__ __launch_bounds__(256) void gemm_bf16_bt64(const unsigned short* __restrict__ A,
                                                      const unsigned short* __restrict__ Bt,
                                                      OT* __restrict__ C,
                                                      int M, int N, int K, int ldc) {
  __shared__ unsigned short As[BM * BK];
  __shared__ unsigned short Bs[64 * BK];

  const int tid = threadIdx.x;
  const int lane = tid & 63;
  const int wave = tid >> 6;
  const int m0 = blockIdx.y * BM;
  const int n0 = blockIdx.x * 64;

  const int qm = (wave >> 1) * 64;
  const int qn = (wave & 1) * 32;
  const int l15 = lane & 15;
  const int quad = lane >> 4;

  const int st_row = lane >> 2;
  const int st_col = (lane & 3) * 8;

  f32x4 acc[4][2] = {};

  for (int k0 = 0; k0 < K; k0 += BK) {
#pragma unroll
    for (int p = 0; p < 2; ++p) {
      const int rb = p * 64 + wave * 16;
      gload16(A + (size_t)(m0 + rb + st_row) * K + k0 + st_col, &As[rb * BK]);
    }
    {
      const int rb = wave * 16;
      gload16(Bt + (size_t)(n0 + rb + st_row) * K + k0 + st_col, &Bs[rb * BK]);
    }
    __syncthreads();

    s16x8 a[4], b[2];
#pragma unroll
    for (int i = 0; i < 4; ++i)
      a[i] = *(const s16x8*)&As[(qm + i * 16 + l15) * BK + quad * 8];
#pragma unroll
    for (int j = 0; j < 2; ++j)
      b[j] = *(const s16x8*)&Bs[(qn + j * 16 + l15) * BK + quad * 8];
#pragma unroll
    for (int i = 0; i < 4; ++i)
#pragma unroll
      for (int j = 0; j < 2; ++j)
        acc[i][j] = __builtin_amdgcn_mfma_f32_16x16x32_bf16(a[i], b[j], acc[i][j], 0, 0, 0);
    __syncthreads();
  }

#pragma unroll
  for (int i = 0; i < 4; ++i) {
    const int row_base = m0 + qm + i * 16 + quad * 4;
#pragma unroll
    for (int j = 0; j < 2; ++j) {
      const int col = n0 + qn + j * 16 + l15;
      if constexpr (MODE == 0) {
#pragma unroll
        for (int r = 0; r < 4; ++r)
          C[(size_t)(row_base + r) * ldc + col] = acc[i][j][r];
      } else {
        ushort4 u;
        u.x = f2bf(acc[i][j][0]); u.y = f2bf(acc[i][j][1]);
        u.z = f2bf(acc[i][j][2]); u.w = f2bf(acc[i][j][3]);
        *(ushort4*)((unsigned short*)C + (size_t)col * ldc + row_base) = u;
      }
    }
  }
}

// ---------------------------------------------------------------------------
// Split-precision bf16 MFMA GEMM: C = (Ahi+Alo) * (Bhi+Blo)^T, dropping lo*lo.
// ---------------------------------------------------------------------------
__global__ __launch_bounds__(256) void gemm_split_bt(const unsigned short* __restrict__ Ahi,
                                                     const unsigned short* __restrict__ Alo,
                                                     const unsigned short* __restrict__ Bhi,
                                                     const unsigned short* __restrict__ Blo,
                                                     float* __restrict__ C,
                                                     int M, int N, int K, int ldc) {
  __shared__ unsigned short AsH[BM * BK];
  __shared__ unsigned short AsL[BM * BK];
  __shared__ unsigned short BsH[BN * BK];
  __shared__ unsigned short BsL[BN * BK];

  const int tid = threadIdx.x;
  const int lane = tid & 63;
  const int wave = tid >> 6;
  const int m0 = blockIdx.y * BM;
  const int n0 = blockIdx.x * BN;

  const int qm = (wave >> 1) * 64;
  const int qn = (wave & 1) * 64;
  const int l15 = lane & 15;
  const int quad = lane >> 4;

  const int st_row = lane >> 2;
  const int st_col = (lane & 3) * 8;

  f32x4 acc[4][4] = {};

  for (int k0 = 0; k0 < K; k0 += BK) {
#pragma unroll
    for (int p = 0; p < 2; ++p) {
      const int rb = p * 64 + wave * 16;
      const size_t aoff = (size_t)(m0 + rb + st_row) * K + k0 + st_col;
      const size_t boff = (size_t)(n0 + rb + st_row) * K + k0 + st_col;
      gload16(Ahi + aoff, &AsH[rb * BK]);
      gload16(Alo + aoff, &AsL[rb * BK]);
      gload16(Bhi + boff, &BsH[rb * BK]);
      gload16(Blo + boff, &BsL[rb * BK]);
    }
    __syncthreads();

    s16x8 ah[4], al[4], bh[4], bl[4];
#pragma unroll
    for (int i = 0; i < 4; ++i) {
      const int ro = (qm + i * 16 + l15) * BK + quad * 8;
      ah[i] = *(const s16x8*)&AsH[ro];
      al[i] = *(const s16x8*)&AsL[ro];
    }
#pragma unroll
    for (int j = 0; j < 4; ++j) {
      const int ro = (qn + j * 16 + l15) * BK + quad * 8;
      bh[j] = *(const s16x8*)&BsH[ro];
      bl[j] = *(const s16x8*)&BsL[ro];
    }
#pragma unroll
    for (int i = 0; i < 4; ++i)
#pragma unroll
      for (int j = 0; j < 4; ++j) {
        acc[i][j] = __builtin_amdgcn_mfma_f32_16x16x32_bf16(ah[i], bh[j], acc[i][j], 0, 0, 0);
        acc[i][j] = __builtin_amdgcn_mfma_f32_16x16x32_bf16(ah[i], bl[j], acc[i][j], 0, 0, 0);
        acc[i][j] = __builtin_amdgcn_mfma_f32_16x16x32_bf16(al[i], bh[j], acc[i][j], 0, 0, 0);
      }
    __syncthreads();
  }

#pragma unroll
  for (int i = 0; i < 4; ++i) {
    const int row_base = m0 + qm + i * 16 + quad * 4;
#pragma unroll
    for (int j = 0; j < 4; ++j) {
      const int col = n0 + qn + j * 16 + l15;
#pragma unroll
      for (int r = 0; r < 4; ++r)
        C[(size_t)(row_base + r) * ldc + col] = acc[i][j][r];
    }
  }
}

// ---------------------------------------------------------------------------
// Fused RMSNorm + RoPE, wave-per-row shfl version (no LDS, no barriers).
// qk fp32 [S][3072] (q cols 0..2047, k cols 2048..3071). Lane i holds d=i and
// d=i+64 -- exactly the rotate_half partner pair, so RoPE is in-lane. cos/sin
// halves are identical (emb = concat(freqs,freqs)), one load serves both.
// grid (S, 6), block 256 = 4 waves; wave handles head hh = by*4+wave.
// ---------------------------------------------------------------------------
__global__ __launch_bounds__(256) void rmsnorm_rope_split(const float* __restrict__ qk,
                                                          const float* __restrict__ cosb,
                                                          const float* __restrict__ sinb,
                                                          unsigned short* __restrict__ qh,
                                                          unsigned short* __restrict__ ql,
                                                          unsigned short* __restrict__ kh,
                                                          unsigned short* __restrict__ kl) {
  const int s = blockIdx.x;
  const int wave = threadIdx.x >> 6;
  const int lane = threadIdx.x & 63;
  const int hh = blockIdx.y * 4 + wave;
  const bool is_q = (hh < 16);
  const int col = is_q ? hh * HD : 2048 + (hh - 16) * HD;

  const float* row = qk + (size_t)s * 3072 + col;
  const float x1 = row[lane];
  const float x2 = row[lane + 64];

  float ss = x1 * x1 + x2 * x2;
  ss += __shfl_xor(ss, 1);
  ss += __shfl_xor(ss, 2);
  ss += __shfl_xor(ss, 4);
  ss += __shfl_xor(ss, 8);
  ss += __shfl_xor(ss, 16);
  ss += __shfl_xor(ss, 32);
  const float r = rsqrtf(ss / 128.f + EPS);

  const float c = cosb[(size_t)s * HD + lane];
  const float sn = sinb[(size_t)s * HD + lane];
  float o1 = x1 * r * c - x2 * r * sn;   // d = lane
  float o2 = x2 * r * c + x1 * r * sn;   // d = lane + 64
  if (is_q) { o1 *= QK_SCALE; o2 *= QK_SCALE; }

  const unsigned short h1 = f2bf(o1), l1 = f2bf(o1 - bf2f(h1));
  const unsigned short h2 = f2bf(o2), l2 = f2bf(o2 - bf2f(h2));
  if (is_q) {
    const size_t base = (size_t)s * 2048 + hh * HD + lane;
    qh[base] = h1; ql[base] = l1;
    qh[base + 64] = h2; ql[base + 64] = l2;
  } else {
    const size_t base = (size_t)s * 1024 + (hh - 16) * HD + lane;
    kh[base] = h1; kl[base] = l1;
    kh[base + 64] = h2; kl[base + 64] = l2;
  }
}

// ---------------------------------------------------------------------------
// Flash attention, MFMA, 2x2 wave partition + DMA staging + swizzled LDS.
// __launch_bounds__(256, 2) keeps 2 blocks/CU. This round: the per-tile
// l-sum shfl reduction is DEFERRED -- l_i stays per-lane-partial (alpha is
// row-uniform so linearity holds) and is reduced once in the epilogue,
// halving per-tile cross-lane traffic.
// ---------------------------------------------------------------------------
#define FA_N 64

__global__ __launch_bounds__(256, 2) void attn_flash_mfma(const unsigned short* __restrict__ qh,
                                                          const unsigned short* __restrict__ ql,
                                                          const unsigned short* __restrict__ kh,
                                                          const unsigned short* __restrict__ kl,
                                                          const unsigned short* __restrict__ vt,
                                                          unsigned short* __restrict__ out) {
  const int h = blockIdx.y;
  const int kvh = h >> 1;
  const int m0 = blockIdx.x * 64;
  const int tid = threadIdx.x;
  const int lane = tid & 63;
  const int wave = tid >> 6;
  const int rg = wave >> 1;   // row group (32 q-rows)
  const int kg = wave & 1;    // key half (32 of 64 keys)
  const int l15 = lane & 15;
  const int quad = lane >> 4;

  __shared__ char smem[59392];
  unsigned short* Kh = (unsigned short*)(smem);
  unsigned short* Kl = (unsigned short*)(smem + 16384);
  unsigned short* Vt = (unsigned short*)(smem + 32768);
  unsigned short* Pt = (unsigned short*)(smem + 49152) + wave * 1280;  // [32][40]

  // ---- Q fragments in registers (A-layout), once ----
  s16x8 qah[2][4], qal[2][4];
#pragma unroll
  for (int rt = 0; rt < 2; ++rt) {
    const int qrow = m0 + rg * 32 + rt * 16 + l15;
#pragma unroll
    for (int ks = 0; ks < 4; ++ks) {
      const size_t off = (size_t)qrow * 2048 + h * HD + ks * 32 + quad * 8;
      qah[rt][ks] = *(const s16x8*)(qh + off);
      qal[rt][ks] = *(const s16x8*)(ql + off);
    }
  }

  f32x4 O[2][8] = {};
  float m_i[2][4], l_i[2][4];
#pragma unroll
  for (int rt = 0; rt < 2; ++rt)
#pragma unroll
    for (int r = 0; r < 4; ++r) { m_i[rt][r] = -1e30f; l_i[rt][r] = 0.f; }

  for (int n0 = 0; n0 < S; n0 += FA_N) {
    __syncthreads();  // previous tile's fragment reads done
    // ---- DMA staging (swizzle chunk ^ row-low-bits) ----
#pragma unroll
    for (int p = 0; p < 4; ++p) {
      const int krow = wave * 16 + p * 4 + (lane >> 4);
      const int kc = (lane & 15) ^ (krow & 15);
      const size_t ksrc = (size_t)(n0 + krow) * 1024 + kvh * HD + kc * 8;
      const int kdst = (wave * 16 + p * 4) * 128;
      gload16(kh + ksrc, Kh + kdst);
      gload16(kl + ksrc, Kl + kdst);
      const int d = wave * 32 + p * 8 + (lane >> 3);
      const int vc = (lane & 7) ^ (d & 7);
      const size_t vsrc = (size_t)(kvh * HD + d) * 2048 + n0 + vc * 8;
      const int vdst = (wave * 32 + p * 8) * 64;
      gload16(vt + vsrc, Vt + vdst);
    }
    __syncthreads();

    // ---- S = Q K^T over this wave's 32-key half, split precision ----
    f32x4 sacc[2][2] = {};
#pragma unroll
    for (int ks = 0; ks < 4; ++ks) {
      s16x8 bh[2], bl[2];
#pragma unroll
      for (int j = 0; j < 2; ++j) {
        const int row = kg * 32 + j * 16 + l15;
        const int cp = ((ks * 4 + quad) ^ l15) * 8;
        const int ro = row * 128 + cp;
        bh[j] = *(const s16x8*)&Kh[ro];
        bl[j] = *(const s16x8*)&Kl[ro];
      }
#pragma unroll
      for (int rt = 0; rt < 2; ++rt)
#pragma unroll
        for (int j = 0; j < 2; ++j) {
          sacc[rt][j] = __builtin_amdgcn_mfma_f32_16x16x32_bf16(qah[rt][ks], bh[j], sacc[rt][j], 0, 0, 0);
          sacc[rt][j] = __builtin_amdgcn_mfma_f32_16x16x32_bf16(qah[rt][ks], bl[j], sacc[rt][j], 0, 0, 0);
          sacc[rt][j] = __builtin_amdgcn_mfma_f32_16x16x32_bf16(qal[rt][ks], bh[j], sacc[rt][j], 0, 0, 0);
        }
    }

    // ---- online softmax; only the MAX is reduced per tile; l stays
    //      per-lane-partial (reduced once in epilogue) ----
#pragma unroll
    for (int rt = 0; rt < 2; ++rt) {
#pragma unroll
      for (int r = 0; r < 4; ++r) {
        float mt = fmaxf(sacc[rt][0][r], sacc[rt][1][r]);
        mt = fmaxf(mt, __shfl_xor(mt, 1));
        mt = fmaxf(mt, __shfl_xor(mt, 2));
        mt = fmaxf(mt, __shfl_xor(mt, 4));
        mt = fmaxf(mt, __shfl_xor(mt, 8));
        const float mnew = fmaxf(m_i[rt][r], mt);
        const float alpha = __expf(m_i[rt][r] - mnew);
        m_i[rt][r] = mnew;
        const float p0 = __expf(sacc[rt][0][r] - mnew);
        const float p1 = __expf(sacc[rt][1][r] - mnew);
        l_i[rt][r] = l_i[rt][r] * alpha + (p0 + p1);
#pragma unroll
        for (int jd = 0; jd < 8; ++jd) O[rt][jd][r] *= alpha;
        const int prow = rt * 16 + quad * 4 + r;
        Pt[prow * 40 + l15] = f2bf(p0);
        Pt[prow * 40 + 16 + l15] = f2bf(p1);
      }
    }
    // no barrier: Pt is per-wave private; DS ops within a wave are ordered.

    // ---- O += P V over this wave's 32 keys ----
    s16x8 pa[2];
#pragma unroll
    for (int rt = 0; rt < 2; ++rt)
      pa[rt] = *(const s16x8*)&Pt[(rt * 16 + l15) * 40 + quad * 8];
#pragma unroll
    for (int jd = 0; jd < 8; ++jd) {
      const int d = jd * 16 + l15;
      const int cp = ((kg * 4 + quad) ^ (d & 7)) * 8;
      const s16x8 vb = *(const s16x8*)&Vt[d * 64 + cp];
#pragma unroll
      for (int rt = 0; rt < 2; ++rt)
        O[rt][jd] = __builtin_amdgcn_mfma_f32_16x16x32_bf16(pa[rt], vb, O[rt][jd], 0, 0, 0);
    }
  }

  // ---- deferred l reduction (once instead of per tile) ----
#pragma unroll
  for (int rt = 0; rt < 2; ++rt)
#pragma unroll
    for (int r = 0; r < 4; ++r) {
      float ls = l_i[rt][r];
      ls += __shfl_xor(ls, 1);
      ls += __shfl_xor(ls, 2);
      ls += __shfl_xor(ls, 4);
      ls += __shfl_xor(ls, 8);
      l_i[rt][r] = ls;
    }

  // ---- merge the two key-halves per row group, then store ----
  __syncthreads();  // all fragment reads done; reuse LDS
  float* Om = (float*)smem;                 // [2 rg][32 rows][128]
  float* ms = (float*)(smem + 32768);       // [2][32]
  float* ls2 = (float*)(smem + 33024);      // [2][32]

  if (kg == 1) {
#pragma unroll
    for (int rt = 0; rt < 2; ++rt)
#pragma unroll
      for (int r = 0; r < 4; ++r) {
        const int row = rt * 16 + quad * 4 + r;
        if (l15 == 0) {
          ms[rg * 32 + row] = m_i[rt][r];
          ls2[rg * 32 + row] = l_i[rt][r];
        }
#pragma unroll
        for (int jd = 0; jd < 8; ++jd)
          Om[(size_t)(rg * 32 + row) * 128 + jd * 16 + l15] = O[rt][jd][r];
      }
  }
  __syncthreads();
  if (kg == 0) {
#pragma unroll
    for (int rt = 0; rt < 2; ++rt)
#pragma unroll
      for (int r = 0; r < 4; ++r) {
        const int row = rt * 16 + quad * 4 + r;
        const float mB = ms[rg * 32 + row];
        const float lB = ls2[rg * 32 + row];
        const float mS = fmaxf(m_i[rt][r], mB);
        const float aA = __expf(m_i[rt][r] - mS);
        const float aB = __expf(mB - mS);
        const float inv = 1.f / (aA * l_i[rt][r] + aB * lB);
        const int grow = m0 + rg * 32 + row;
#pragma unroll
        for (int jd = 0; jd < 8; ++jd) {
          const float oB = Om[(size_t)(rg * 32 + row) * 128 + jd * 16 + l15];
          out[(size_t)grow * 2048 + h * HD + jd * 16 + l15] =
              f2bf((aA * O[rt][jd][r] + aB * oB) * inv);
        }
      }
  }
}

// ---------------------------------------------------------------------------
extern "C" void kernel_launch(void* const* d_in, const int* in_sizes, int n_in,
                              void* d_out, int out_size, void* d_ws, size_t ws_size,
                              hipStream_t stream) {
  const float* hidden = (const float*)d_in[0];  // [S][HID]
  const float* cosb   = (const float*)d_in[1];  // [S][HD]
  const float* sinb   = (const float*)d_in[2];  // [S][HD]
  const float* wq     = (const float*)d_in[3];  // [HID][2048]
  const float* wk     = (const float*)d_in[4];  // [HID][1024]
  const float* wv     = (const float*)d_in[5];  // [HID][1024]
  const float* wo     = (const float*)d_in[6];  // [2048][HID]
  float* out = (float*)d_out;                   // [S][HID]

  // Workspace map (72 MB, regions reused once dead):
  char* w = (char*)d_ws;
  float* qk_buf           = (float*)(w);                          //  0-24 MB fp32 [S][3072]
  unsigned short* wqkT_hi = (unsigned short*)(w + (24u << 20));   // 24-36 (dead after QK gemm)
  unsigned short* wqkT_lo = (unsigned short*)(w + (36u << 20));   // 36-48 (dead after QK gemm)
  unsigned short* hid_hi  = (unsigned short*)(w + (48u << 20));   // 48-56 (dead after V gemm)
  unsigned short* hid_lo  = (unsigned short*)(w + (56u << 20));   // 56-64 (dead after QK gemm)
  unsigned short* vt_b    = (unsigned short*)(w + (64u << 20));   // 64-68 V^T bf16 [1024][2048]
  unsigned short* wvT     = (unsigned short*)(w + (68u << 20));   // 68-72
  // reuse after QK gemm:
  unsigned short* q_hi    = (unsigned short*)(w + (24u << 20));   // 24-32 [S][2048]
  unsigned short* q_lo    = (unsigned short*)(w + (32u << 20));   // 32-40
  unsigned short* k_hi    = (unsigned short*)(w + (40u << 20));   // 40-44 [S][1024]
  unsigned short* k_lo    = (unsigned short*)(w + (44u << 20));   // 44-48
  // reuse after V gemm:
  unsigned short* woT     = (unsigned short*)(w + (48u << 20));   // 48-56 [2048][2048]
  unsigned short* a_b     = (unsigned short*)(w + (56u << 20));   // 56-64 [S][2048]

  dim3 blk(256);

  // prologue
  f32_to_bf16_split<<<dim3((S * HID / 4 + 255) / 256), blk, 0, stream>>>(hidden, hid_hi, hid_lo, S * HID / 4);
  transpose_to_bf16_split<<<dim3(32, 32), blk, 0, stream>>>(wq, wqkT_hi, wqkT_lo, HID, 2048);
  transpose_to_bf16_split<<<dim3(16, 32), blk, 0, stream>>>(wk, wqkT_hi + (size_t)2048 * 2048,
                                                            wqkT_lo + (size_t)2048 * 2048, HID, 1024);
  transpose_to_bf16<<<dim3(16, 32), blk, 0, stream>>>(wv, wvT, 2048, 1024);

  // QK projection (split precision) -> fp32 [S][3072]
  gemm_split_bt<<<dim3(3072 / BN, S / BM), blk, 0, stream>>>(hid_hi, hid_lo, wqkT_hi, wqkT_lo,
                                                             qk_buf, S, 3072, HID, 3072);

  // V projection -> transposed bf16 [1024][2048]; 128x64 tile, 256 blocks
  gemm_bf16_bt64<1, unsigned short><<<dim3(1024 / 64, S / BM), blk, 0, stream>>>(
      hid_hi, wvT, vt_b, S, 1024, HID, 2048);

  // wo transpose into dead hid_hi region (after V gemm in stream order)
  transpose_to_bf16<<<dim3(32, 32), blk, 0, stream>>>(wo, woT, 2048, HID);

  // RMSNorm + RoPE -> split bf16 q/k (q pre-scaled); wave-per-row
  rmsnorm_rope_split<<<dim3(S, 6), blk, 0, stream>>>(qk_buf, cosb, sinb, q_hi, q_lo, k_hi, k_lo);

  // MFMA flash attention -> bf16 [S][2048]
  attn_flash_mfma<<<dim3(S / 64, NH), blk, 0, stream>>>(q_hi, q_lo, k_hi, k_lo, vt_b, a_b);

  // output projection -> fp32 out; 128x64 tile, 512 blocks
  gemm_bf16_bt64<0, float><<<dim3(HID / 64, S / BM), blk, 0, stream>>>(
      a_b, woT, out, S, HID, 2048, HID);
}